// Round 5
// baseline (514.526 us; speedup 1.0000x reference)
//
#include <hip/hip_runtime.h>

// TrendGRU R11b: identical to R11 (infra failed; resubmit for measurement).
// Occupancy restructure. R10 showed a single wave/SIMD gets ~zero self-overlap
// (time = trans + VALU + MFMA + drain, summed). 32768/32 = 1024 waves exactly
// fills 1024 SIMDs, so: 16 elems/wave, 2048 blocks -> 2 waves/SIMD
// (independent chains, no sync) so waves hide each other's MFMA + drains.
// MFMA: mfma_f32_16x16x32_bf16 - K=32 covers the whole stream (h0..23 + x-pack
// k24..31) in one step. Per gate 2 M-tiles (units 0-15, 16-23+pad) x hi/lo =
// 12 MFMA/wave-t. Epilogue: 4 grouped-rcp pair_epi (validated in R10).
// h acc->B redistribution: lane (e=lane&15, g=lane>>4) produces packed unit-
// pairs Wd0=pair(2g) Wd1=pair(2g+1) (tile0) Wd2=pair(8+2g) Wd3=pair(9+2g)
// (tile1, g<2); B-frag lane (e,g') needs pairs [4g'..4g'+3] -> 8 ds_bpermute +
// cndmask merges (idx precomputed); g'=3 lanes carry the x/bias K-pack.
// Tile1 pair_epi on g>=2 lanes is wasted issue (A pad rows are zero -> acc 0,
// finite math, outputs never consumed) - the price of 24 units in 16-row tiles.

#define GRU_T 512
#define FS 28   // FC LDS row stride in floats

typedef __attribute__((ext_vector_type(8)))  short bf16x8;
typedef __attribute__((ext_vector_type(4)))  float f32x4;
typedef __attribute__((ext_vector_type(2)))  float f32x2;

__device__ __forceinline__ float bf16hi_f(float v) {   // RNE-to-bf16, as float
    unsigned u = __float_as_uint(v);
    u = (u + 0x7FFFu + ((u >> 16) & 1u)) & 0xFFFF0000u;
    return __uint_as_float(u);
}
__device__ __forceinline__ unsigned bf16_rne(float v) {
    unsigned u = __float_as_uint(v);
    return (u + 0x7FFFu + ((u >> 16) & 1u)) >> 16;
}
// packed RNE f32->bf16: dst = [bf16(lo) | bf16(hi)<<16]
__device__ __forceinline__ unsigned cvt_pk_bf16(float lo, float hi) {
    unsigned r;
    asm("v_cvt_pk_bf16_f32 %0, %1, %2" : "=v"(r) : "v"(lo), "v"(hi));
    return r;
}
__device__ __forceinline__ f32x4 mfma16(bf16x8 a, bf16x8 b, f32x4 c) {
    return __builtin_amdgcn_mfma_f32_16x16x32_bf16(a, b, c, 0, 0, 0);
}

// slot-pair epilogue (grouped rcp, R10-validated): 6 exp2 + 2 rcp per pair.
__device__ __forceinline__ unsigned pair_epi(float ar0, float ar1,
                                             float az0, float az1,
                                             float an0, float an1,
                                             const f32x2 aX, f32x2& h)
{
    const f32x2 one2 = {1.0f, 1.0f};
    f32x2 er2, ez2, ev2;
    er2.x = __builtin_amdgcn_exp2f(-ar0);
    er2.y = __builtin_amdgcn_exp2f(-ar1);
    ez2.x = __builtin_amdgcn_exp2f(-az0);
    ez2.y = __builtin_amdgcn_exp2f(-az1);
    const f32x2 dr2 = er2 + one2;
    const f32x2 dz2 = ez2 + one2;
    const f32x2 pp2 = dr2 * dz2;
    const float  Q  = __builtin_amdgcn_rcpf(pp2.x * pp2.y);
    f32x2 qi2; qi2.x = Q * pp2.y; qi2.y = Q * pp2.x;
    const f32x2 rr2 = qi2 * dz2;
    const f32x2 zz2 = qi2 * dr2;
    const f32x2 an2 = {an0, an1};
    const f32x2 u2  = __builtin_elementwise_fma(rr2, an2, aX);
    ev2.x = __builtin_amdgcn_exp2f(u2.x);
    ev2.y = __builtin_amdgcn_exp2f(u2.y);
    const f32x2 dv2 = ev2 + one2;
    const float  Qn = __builtin_amdgcn_rcpf(dv2.x * dv2.y);
    f32x2 rv2; rv2.x = Qn * dv2.y; rv2.y = Qn * dv2.x;
    const f32x2 m2  = {-2.0f, -2.0f};
    const f32x2 nn2 = __builtin_elementwise_fma(m2, rv2, one2);
    const f32x2 hm2 = h - nn2;
    const f32x2 hn2 = __builtin_elementwise_fma(zz2, hm2, nn2);
    h = hn2;
    return cvt_pk_bf16(hn2.x, hn2.y);
}

__global__ __launch_bounds__(64) void trend_gru_mfma16(
    const float* __restrict__ x,     // (B, T)
    const float* __restrict__ W_ih,  // (72,)
    const float* __restrict__ b_ih,  // (72,)
    const float* __restrict__ W_hh,  // (72, 24) rows r,z,n
    const float* __restrict__ b_hh,  // (72,)
    const float* __restrict__ fc_w,  // (2, 24)
    const float* __restrict__ fc_b,  // (2,)
    float* __restrict__ out)         // (B, 2)
{
    const int lane = threadIdx.x;
    const int e = lane & 15;            // elem (B/C col)
    const int g = lane >> 4;            // k-group / C row-group
    const int elem0 = blockIdx.x * 16;

    __shared__ __align__(16) float Flds[16 * FS];

    const float L2E = 1.4426950408889634f;

    // ---- A fragments: A[gate][tile][hi/lo]; row m = tile*16 + e,
    // k = 8*g + i (contiguous-8 per lane group, as verified for 32x32x16) ----
    bf16x8 A[3][2][2];
#pragma unroll
    for (int gate = 0; gate < 3; ++gate) {
        const float sc = (gate == 2) ? 2.0f * L2E : L2E;
#pragma unroll
        for (int tile = 0; tile < 2; ++tile) {
            const int m = tile * 16 + e;
            const bool valid = m < 24;
            const int R = gate * 24 + (valid ? m : 0);
            const float wx = (gate < 2 && valid) ? sc * W_ih[R] : 0.0f;
            const float bb = valid ? sc * ((gate < 2) ? (b_ih[R] + b_hh[R]) : b_hh[R]) : 0.0f;
            const float wxh = bf16hi_f(wx), bbh = bf16hi_f(bb);
            bf16x8 fh, fl;
#pragma unroll
            for (int i = 0; i < 8; ++i) {
                const int k = g * 8 + i;
                float vh = 0.0f, vl = 0.0f;
                if (valid && k < 24) {
                    const float w  = sc * W_hh[R * 24 + k];
                    const float wh = bf16hi_f(w);
                    vh = wh; vl = w - wh;
                } else if (valid) {
                    if (k == 24 || k == 25)      vh = wxh;       // Wih_hi*(x_hi,x_lo)
                    else if (k == 26)            vh = wx - wxh;  // Wih_lo*x_hi
                    else if (k == 27)            vh = bbh;       // b_hi*1
                    else if (k == 28)            vh = bb - bbh;  // b_lo*1
                }
                fh[i] = (short)bf16_rne(vh);
                fl[i] = (short)bf16_rne(vl);
            }
            A[gate][tile][0] = fh;
            A[gate][tile][1] = fl;
        }
    }

    // ---- per-pair n-gate x-path constants (exact fp32) ----
    // pair p: units j = (p<2 ? 4g+2p+c : 16+4g+2(p-2)+c)
    f32x2 wn2[4], bn2[4];
#pragma unroll
    for (int p = 0; p < 4; ++p) {
#pragma unroll
        for (int c = 0; c < 2; ++c) {
            int j = (p < 2) ? (4 * g + 2 * p + c) : (16 + 4 * g + 2 * (p - 2) + c);
            if (j > 23) j = 23;   // g>=2 tile1 lanes: unused, keep in-bounds
            wn2[p][c] = 2.0f * L2E * W_ih[48 + j];
            bn2[p][c] = 2.0f * L2E * b_ih[48 + j];
        }
    }

    const float* xp = x + (size_t)(elem0 + e) * GRU_T;
    float xv = xp[0];

    f32x2 h2[4];
#pragma unroll
    for (int p = 0; p < 4; ++p) { h2[p].x = 0.0f; h2[p].y = 0.0f; }

    f32x2 aX2[4];
#pragma unroll
    for (int p = 0; p < 4; ++p) {
        const f32x2 xb = {xv, xv};
        aX2[p] = __builtin_elementwise_fma(wn2[p], xb, bn2[p]);
    }

    // packed h unit-pair dwords (h=0 -> all zero)
    unsigned Wd0 = 0, Wd1 = 0, Wd2 = 0, Wd3 = 0;

    // bperm byte-indices (src lane * 4), precomputed:
    // B dwords 0/1 come from src lane e + 32*[g'==1] (tile0) or e (tile1,g'==2);
    // B dwords 2/3 from e+16 + 32*[g'==1] / e+16.
    const int idxA = (e + ((g & 1) << 5)) << 2;
    const int idxB = idxA + (16 << 2);
    const int idxC = e << 2;
    const int idxD = (e + 16) << 2;
    const bool mg2 = (g == 2);
    const bool mg3 = (g == 3);

    const f32x4 z4 = {0.f, 0.f, 0.f, 0.f};

#pragma unroll 1
    for (int t = 0; t < GRU_T; ++t) {
        // ---- B fragment: 8 bperm + merges; g==3 lanes carry x/bias pack ----
        const unsigned xy = cvt_pk_bf16(xv, 1.0f);        // k26=x_hi k27=1.0
        const float    xh = __uint_as_float(xy << 16);
        const unsigned xx = cvt_pk_bf16(xv, xv - xh);     // k24=x_hi k25=x_lo

        unsigned Bd0 = (unsigned)__builtin_amdgcn_ds_bpermute(idxA, (int)Wd0);
        unsigned Bd1 = (unsigned)__builtin_amdgcn_ds_bpermute(idxA, (int)Wd1);
        unsigned Bd2 = (unsigned)__builtin_amdgcn_ds_bpermute(idxB, (int)Wd0);
        unsigned Bd3 = (unsigned)__builtin_amdgcn_ds_bpermute(idxB, (int)Wd1);
        const unsigned c0 = (unsigned)__builtin_amdgcn_ds_bpermute(idxC, (int)Wd2);
        const unsigned c1 = (unsigned)__builtin_amdgcn_ds_bpermute(idxC, (int)Wd3);
        const unsigned c2 = (unsigned)__builtin_amdgcn_ds_bpermute(idxD, (int)Wd2);
        const unsigned c3 = (unsigned)__builtin_amdgcn_ds_bpermute(idxD, (int)Wd3);
        Bd0 = mg2 ? c0 : Bd0;  Bd1 = mg2 ? c1 : Bd1;
        Bd2 = mg2 ? c2 : Bd2;  Bd3 = mg2 ? c3 : Bd3;
        Bd0 = mg3 ? xx : Bd0;  Bd1 = mg3 ? xy : Bd1;
        Bd2 = mg3 ? 0x00003F80u : Bd2;  Bd3 = mg3 ? 0u : Bd3;
        uint4 bq; bq.x = Bd0; bq.y = Bd1; bq.z = Bd2; bq.w = Bd3;
        const bf16x8 Bf = *(const bf16x8*)&bq;
        const float xnext = xp[(t + 1 < GRU_T) ? t + 1 : t];

        // ---- 12 MFMA 16x16x32: 3 gates x 2 tiles x hi/lo ----
        f32x4 cR0 = mfma16(A[0][0][0], Bf, z4); cR0 = mfma16(A[0][0][1], Bf, cR0);
        f32x4 cZ0 = mfma16(A[1][0][0], Bf, z4); cZ0 = mfma16(A[1][0][1], Bf, cZ0);
        f32x4 cN0 = mfma16(A[2][0][0], Bf, z4); cN0 = mfma16(A[2][0][1], Bf, cN0);
        f32x4 cR1 = mfma16(A[0][1][0], Bf, z4); cR1 = mfma16(A[0][1][1], Bf, cR1);
        f32x4 cZ1 = mfma16(A[1][1][0], Bf, z4); cZ1 = mfma16(A[1][1][1], Bf, cZ1);
        f32x4 cN1 = mfma16(A[2][1][0], Bf, z4); cN1 = mfma16(A[2][1][1], Bf, cN1);

        // ---- epilogue: tile0 pairs (all lanes valid), tile1 pairs (g<2 valid;
        // g>=2 compute on zeros, outputs never consumed) ----
        Wd0 = pair_epi(cR0[0], cR0[1], cZ0[0], cZ0[1], cN0[0], cN0[1], aX2[0], h2[0]);
        Wd1 = pair_epi(cR0[2], cR0[3], cZ0[2], cZ0[3], cN0[2], cN0[3], aX2[1], h2[1]);
        Wd2 = pair_epi(cR1[0], cR1[1], cZ1[0], cZ1[1], cN1[0], cN1[1], aX2[2], h2[2]);
        Wd3 = pair_epi(cR1[2], cR1[3], cZ1[2], cZ1[3], cN1[2], cN1[3], aX2[3], h2[3]);

        xv = xnext;
#pragma unroll
        for (int p = 0; p < 4; ++p) {
            const f32x2 xb = {xv, xv};
            aX2[p] = __builtin_elementwise_fma(wn2[p], xb, bn2[p]);
        }
    }

    // ---- FC head: h (fp32) -> LDS, lanes 0..15 reduce 24 -> 2 ----
    {
        float4 f4;
        f4.x = h2[0].x; f4.y = h2[0].y; f4.z = h2[1].x; f4.w = h2[1].y;
        *(float4*)(&Flds[e * FS + 4 * g]) = f4;              // units 4g..4g+3
        if (g < 2) {
            float4 f5;
            f5.x = h2[2].x; f5.y = h2[2].y; f5.z = h2[3].x; f5.w = h2[3].y;
            *(float4*)(&Flds[e * FS + 16 + 4 * g]) = f5;     // units 16+4g..
        }
    }
    __builtin_amdgcn_s_barrier();
    if (lane < 16) {
        float o0 = fc_b[0], o1 = fc_b[1];
#pragma unroll
        for (int j = 0; j < 24; ++j) {
            const float hv = Flds[lane * FS + j];
            o0 = fmaf(hv, fc_w[j],      o0);
            o1 = fmaf(hv, fc_w[24 + j], o1);
        }
        float2 o; o.x = o0; o.y = o1;
        *(float2*)(out + (size_t)(elem0 + lane) * 2) = o;
    }
}

extern "C" void kernel_launch(void* const* d_in, const int* in_sizes, int n_in,
                              void* d_out, int out_size, void* d_ws, size_t ws_size,
                              hipStream_t stream) {
    const float* x    = (const float*)d_in[0];
    const float* W_ih = (const float*)d_in[1];
    const float* b_ih = (const float*)d_in[2];
    const float* W_hh = (const float*)d_in[3];
    const float* b_hh = (const float*)d_in[4];
    const float* fc_w = (const float*)d_in[5];
    const float* fc_b = (const float*)d_in[6];
    float* out = (float*)d_out;

    const int B = in_sizes[0] / GRU_T;      // 32768
    const int grid = B / 16;                // 2048 blocks x 1 wave, 2 waves/SIMD
    trend_gru_mfma16<<<grid, 64, 0, stream>>>(x, W_ih, b_ih, W_hh, b_hh,
                                              fc_w, fc_b, out);
}